// Round 1
// 663.008 us; speedup vs baseline: 1.2566x; 1.2566x over previous
//
#include <hip/hip_runtime.h>
#include <math.h>

// LurieNet: X_{t+1} = X_t + h*(A X_t + B tanh(C X_t + by) + bx), 511 steps,
// state (128 x 512 batch), output (512, 512, 128) fp32.
// Reformulated with Y := C X + by as state:  S = [X; Y] (256 x 512),
//   V = [X_bf16; tanh(Y)],  S += h*(M V) + h*b2,  M = [[A,B],[CA,CB]].
// Pipeline: k_expm (5 expm) -> k_abc (A,B,C) -> k_mid (CA,CB,Y0,t0-out,cbx)
//           -> k_pack (bf16 hi/lo fragment packing) -> k_main (511-step loop).

typedef __attribute__((ext_vector_type(8))) short short8;
typedef __attribute__((ext_vector_type(4))) float f32x4;

// workspace layout (float units)
#define OFF_UO   0            // 5 * 16384 : UA_o, UB_o, VB_o, UC_o, VC_o
#define OFF_A    81920
#define OFF_B    98304
#define OFF_C    114688
#define OFF_CA   131072
#define OFF_CB   147456
#define OFF_Y0   163840       // 128 x 512
#define OFF_CBX  229376       // 128
#define OFF_HBP  229504       // 16*64*4
#define OFF_S0P  233600       // 256*512
#define OFF_MF   364672       // ushort area: 131072 bf16

__device__ __forceinline__ unsigned short f2bf(float x){
  unsigned int u = __float_as_uint(x);
  unsigned int r = u + 0x7FFFu + ((u >> 16) & 1u);   // RNE
  return (unsigned short)(r >> 16);
}
__device__ __forceinline__ float bf2f(unsigned short b){
  return __uint_as_float(((unsigned int)b) << 16);
}
__device__ __forceinline__ void split_bf(float x, unsigned short& h, unsigned short& l){
  h = f2bf(x);
  l = f2bf(x - bf2f(h));
}
__device__ __forceinline__ f32x4 mfma16(short8 a, short8 b, f32x4 c){
  return __builtin_amdgcn_mfma_f32_16x16x32_bf16(a, b, c, 0, 0, 0);
}
// Branchless tanh: 1 - 2/(exp(2y)+1). v_exp + v_rcp, no divergence.
// |err| ~1e-7 absolute, far below bf16 rounding of V. inf-safe both tails.
__device__ __forceinline__ float tanh_fast(float y){
  float e = __expf(2.f * y);
  return 1.f - 2.f * __builtin_amdgcn_rcpf(e + 1.f);
}

// ---------------- K1: 5 x expm(skew(Z)) via Taylor-12 Horner, hi/lo bf16 MFMA
// (Taylor-12: remainder <= ||R||^13/13! ~ 6e-10 at ||R||<=1; hi/lo roundoff
//  ~1e-5 dominates, so terms 13..16 were pure overhead.)
__global__ __launch_bounds__(1024) void k_expm(
    const float* __restrict__ UA, const float* __restrict__ UB,
    const float* __restrict__ VB, const float* __restrict__ UC,
    const float* __restrict__ VC, float* __restrict__ ws)
{
  const int b = blockIdx.x;
  const float* Z = (b==0)?UA:((b==1)?UB:((b==2)?VB:((b==3)?UC:VC)));
  float* Eo = ws + OFF_UO + b*16384;

  __shared__ unsigned short Hh[2][128][136];  // H^T (n-major), bf16 hi
  __shared__ unsigned short Hl[2][128][136];  // bf16 lo

  const int tid = threadIdx.x, lane = tid & 63, w = tid >> 6;
  const int q = lane >> 4, m16 = lane & 15;
  const int rt = w >> 2, cp = w & 3;          // wave: rows [32rt,32rt+32), cols [32cp,32cp+32)

  // A-operand frags of R = skew(Z): lane holds A[m=lane&15][k = 8*(lane>>4)+j]
  short8 Rh[2][4], Rl[2][4];
  #pragma unroll
  for (int rr=0; rr<2; ++rr){
    const int row = rt*32 + rr*16 + m16;
    #pragma unroll
    for (int c=0; c<4; ++c){
      short8 hh, ll;
      #pragma unroll
      for (int j=0; j<8; ++j){
        const int k = c*32 + q*8 + j;
        float z = 0.f;
        if (row < k)      z =  Z[row*128 + k];
        else if (row > k) z = -Z[k*128 + row];
        unsigned short hb_, lb_;
        split_bf(z, hb_, lb_);
        hh[j] = (short)hb_; ll[j] = (short)lb_;
      }
      Rh[rr][c] = hh; Rl[rr][c] = ll;
    }
  }
  { // H = I into buffer 0
    unsigned short* hp = &Hh[0][0][0];
    unsigned short* lp = &Hl[0][0][0];
    for (int idx = tid; idx < 128*136; idx += 1024){
      const int n = idx / 136, k = idx - n*136;
      hp[idx] = (n == k) ? (unsigned short)0x3F80u : (unsigned short)0u;
      lp[idx] = 0u;
    }
  }
  __syncthreads();

  int cur = 0;
  for (int j = 12; j >= 1; --j){          // H = I + (R*H)/j
    const float rj = 1.f / (float)j;
    f32x4 acc[2][2];
    #pragma unroll
    for (int rr=0; rr<2; ++rr)
      #pragma unroll
      for (int cc=0; cc<2; ++cc) acc[rr][cc] = (f32x4){0.f,0.f,0.f,0.f};

    #pragma unroll
    for (int cc=0; cc<2; ++cc){
      const int n = cp*32 + cc*16 + m16;
      #pragma unroll
      for (int c=0; c<4; ++c){
        const short8 bh = *(const short8*)&Hh[cur][n][c*32 + q*8];
        const short8 bl = *(const short8*)&Hl[cur][n][c*32 + q*8];
        #pragma unroll
        for (int rr=0; rr<2; ++rr){
          acc[rr][cc] = mfma16(Rh[rr][c], bh, acc[rr][cc]);
          acc[rr][cc] = mfma16(Rl[rr][c], bh, acc[rr][cc]);
          acc[rr][cc] = mfma16(Rh[rr][c], bl, acc[rr][cc]);
        }
      }
    }
    if (j > 1){
      const int nxt = cur ^ 1;
      #pragma unroll
      for (int rr=0; rr<2; ++rr){
        #pragma unroll
        for (int cc=0; cc<2; ++cc){
          const int cg  = cp*32 + cc*16 + m16;
          const int rg0 = rt*32 + rr*16 + q*4;
          union { unsigned int u[2]; unsigned short s[4]; } ph, pl;
          #pragma unroll
          for (int i=0; i<4; ++i){
            float x = acc[rr][cc][i]*rj + ((rg0+i)==cg ? 1.f : 0.f);
            unsigned short hb_, lb_; split_bf(x, hb_, lb_);
            ph.s[i] = hb_; pl.s[i] = lb_;
          }
          *(uint2*)&Hh[nxt][cg][rg0] = make_uint2(ph.u[0], ph.u[1]);
          *(uint2*)&Hl[nxt][cg][rg0] = make_uint2(pl.u[0], pl.u[1]);
        }
      }
      __syncthreads();
      cur = nxt;
    } else {
      #pragma unroll
      for (int rr=0; rr<2; ++rr){
        #pragma unroll
        for (int cc=0; cc<2; ++cc){
          const int cg  = cp*32 + cc*16 + m16;
          const int rg0 = rt*32 + rr*16 + q*4;
          #pragma unroll
          for (int i=0; i<4; ++i)
            Eo[(rg0+i)*128 + cg] = acc[rr][cc][i] + ((rg0+i)==cg ? 1.f : 0.f);
        }
      }
    }
  }
}

// ---------------- K3: A, B, C  (one 128^3 matmul each, hi/lo 3-product)
__global__ __launch_bounds__(1024) void k_abc(float* __restrict__ ws,
    const float* __restrict__ SBm, const float* __restrict__ SCm,
    const float* __restrict__ GA1, const float* __restrict__ GAk,
    const float* __restrict__ GAp, const float* __restrict__ YA)
{
  const int mat = blockIdx.x;   // 0=A 1=B 2=C
  __shared__ float dvec[128];
  __shared__ float scal[4];
  __shared__ float sb[128], sc[128];
  const int tid = threadIdx.x;

  const float* U; const float* V; float* Out;
  if (mat == 0){ U = ws + OFF_UO;          V = U;                    Out = ws + OFF_A; }
  else if (mat == 1){ U = ws + OFF_UO + 16384; V = ws + OFF_UO + 32768; Out = ws + OFF_B; }
  else { U = ws + OFF_UO + 49152; V = ws + OFF_UO + 65536; Out = ws + OFF_C; }

  if (mat == 0){
    // parallel stage of the diagonals (latency-parallel global loads),
    // then a cheap LDS-only top-2 scan (was: 256 serial strided global loads).
    if (tid < 128){ sb[tid] = fabsf(SBm[tid*129]); sc[tid] = fabsf(SCm[tid*129]); }
    __syncthreads();
    if (tid == 0){
      float b1=0.f,b2=0.f,c1=0.f,c2=0.f;
      for (int i=0;i<128;++i){
        float vb = sb[i];
        if (vb > b1){ b2=b1; b1=vb; } else if (vb > b2) b2=vb;
        float vc = sc[i];
        if (vc > c1){ c2=c1; c1=vc; } else if (vc > c2) c2=vc;
      }
      float alpha = sqrtf(8.f*(b1*b1*c1*c1 + b2*b2*c2*c2));  // 4*K*G^2 = 8
      float sa0 = GA1[0];
      float sa2 = -(alpha + sa0) - (fabsf(GAk[0]) + 1e-5f);
      float mm  = fminf(fminf(sa0, sa2), 0.f);               // min over block-diag incl. zeros
      scal[0]=sa0; scal[1]=sa2; scal[2]=mm;
    }
    __syncthreads();
    if (tid < 128){
      float v;
      if (tid == 0) v = scal[0];
      else if (tid == 1) v = scal[1];
      else v = scal[2] - fabsf(GAp[(tid-2)*127]);  // diag of (126x126)
      dvec[tid] = v;
    }
  } else {
    const float* Sm = (mat == 1) ? SBm : SCm;
    if (tid < 128) dvec[tid] = fabsf(Sm[tid*129]);
  }
  __syncthreads();

  const int lane = tid & 63, w = tid >> 6, q = lane >> 4, m16 = lane & 15;
  const int rt = w >> 2, cp = w & 3;

  short8 Ah[2][4], Al[2][4];
  #pragma unroll
  for (int rr=0; rr<2; ++rr){
    const int row = rt*32 + rr*16 + m16;
    #pragma unroll
    for (int c=0; c<4; ++c){
      const float* up = U + row*128 + c*32 + q*8;
      const f32x4 u0 = *(const f32x4*)up;
      const f32x4 u1 = *(const f32x4*)(up + 4);
      short8 hh, ll;
      #pragma unroll
      for (int jj=0; jj<4; ++jj){
        unsigned short hb_, lb_;
        split_bf(u0[jj], hb_, lb_); hh[jj]   = (short)hb_; ll[jj]   = (short)lb_;
        split_bf(u1[jj], hb_, lb_); hh[jj+4] = (short)hb_; ll[jj+4] = (short)lb_;
      }
      Ah[rr][c] = hh; Al[rr][c] = ll;
    }
  }
  f32x4 acc[2][2];
  #pragma unroll
  for (int rr=0; rr<2; ++rr)
    #pragma unroll
    for (int cc=0; cc<2; ++cc) acc[rr][cc] = (f32x4){0.f,0.f,0.f,0.f};

  #pragma unroll
  for (int cc=0; cc<2; ++cc){
    const int n = cp*32 + cc*16 + m16;
    #pragma unroll
    for (int c=0; c<4; ++c){
      const int k0 = c*32 + q*8;
      const float* vp = V + n*128 + k0;            // B[k][n] = dvec[k]*V[n][k]
      const f32x4 v0 = *(const f32x4*)vp;
      const f32x4 v1 = *(const f32x4*)(vp + 4);
      short8 bh, bl;
      #pragma unroll
      for (int jj=0; jj<4; ++jj){
        unsigned short hb_, lb_;
        split_bf(v0[jj]*dvec[k0+jj],   hb_, lb_); bh[jj]   = (short)hb_; bl[jj]   = (short)lb_;
        split_bf(v1[jj]*dvec[k0+4+jj], hb_, lb_); bh[jj+4] = (short)hb_; bl[jj+4] = (short)lb_;
      }
      #pragma unroll
      for (int rr=0; rr<2; ++rr){
        acc[rr][cc] = mfma16(Ah[rr][c], bh, acc[rr][cc]);
        acc[rr][cc] = mfma16(Al[rr][c], bh, acc[rr][cc]);
        acc[rr][cc] = mfma16(Ah[rr][c], bl, acc[rr][cc]);
      }
    }
  }
  #pragma unroll
  for (int rr=0; rr<2; ++rr){
    #pragma unroll
    for (int cc=0; cc<2; ++cc){
      const int cg  = cp*32 + cc*16 + m16;
      const int rg0 = rt*32 + rr*16 + q*4;
      #pragma unroll
      for (int i=0; i<4; ++i){
        float x = acc[rr][cc][i];
        if (mat == 0){
          const int r = rg0 + i;
          float sk = 0.f;
          if (r < cg) sk = YA[r*128 + cg];
          else if (r > cg) sk = -YA[cg*128 + r];
          x = 0.5f*x + 0.5f*sk;
        }
        Out[(rg0+i)*128 + cg] = x;
      }
    }
  }
}

// ---------------- K4a: CA, CB, Y0 = C X0^T + by, t=0 output, cbx = C bx
__global__ __launch_bounds__(1024) void k_mid(float* __restrict__ ws,
    const float* __restrict__ X0, const float* __restrict__ bx,
    const float* __restrict__ by, float* __restrict__ out)
{
  const int role = blockIdx.x;
  const int tid = threadIdx.x;

  if (role >= 6 && role < 14){   // t=0 output: out[b][0][i] = X0[b][i]
    const int t0 = ((role-6)*1024 + tid) * 8;
    const int bb = t0 >> 7, ii = t0 & 127;
    const f32x4 v0 = *(const f32x4*)(X0 + t0);
    const f32x4 v1 = *(const f32x4*)(X0 + t0 + 4);
    float* dst = out + (size_t)bb*65536 + ii;
    *(f32x4*)dst = v0;
    *(f32x4*)(dst + 4) = v1;
    return;
  }
  if (role == 14){               // cbx = C @ bx
    if (tid < 128){
      const float* Cm = ws + OFF_C;
      float s = 0.f;
      for (int j2=0; j2<128; ++j2) s += Cm[tid*128 + j2]*bx[j2];
      ws[OFF_CBX + tid] = s;
    }
    return;
  }

  const int lane = tid & 63, w = tid >> 6, q = lane >> 4, m16 = lane & 15;
  const int rt = w >> 2, cp = w & 3;
  const float* Cm = ws + OFF_C;

  short8 Ah[2][4], Al[2][4];     // A-op = C rows
  #pragma unroll
  for (int rr=0; rr<2; ++rr){
    const int row = rt*32 + rr*16 + m16;
    #pragma unroll
    for (int c=0; c<4; ++c){
      const float* up = Cm + row*128 + c*32 + q*8;
      const f32x4 u0 = *(const f32x4*)up;
      const f32x4 u1 = *(const f32x4*)(up + 4);
      short8 hh, ll;
      #pragma unroll
      for (int jj=0; jj<4; ++jj){
        unsigned short hb_, lb_;
        split_bf(u0[jj], hb_, lb_); hh[jj]   = (short)hb_; ll[jj]   = (short)lb_;
        split_bf(u1[jj], hb_, lb_); hh[jj+4] = (short)hb_; ll[jj+4] = (short)lb_;
      }
      Ah[rr][c] = hh; Al[rr][c] = ll;
    }
  }
  f32x4 acc[2][2];
  #pragma unroll
  for (int rr=0; rr<2; ++rr)
    #pragma unroll
    for (int cc=0; cc<2; ++cc) acc[rr][cc] = (f32x4){0.f,0.f,0.f,0.f};

  if (role < 2){                 // CA / CB
    const float* Rm = ws + ((role == 0) ? OFF_A : OFF_B);
    #pragma unroll
    for (int cc=0; cc<2; ++cc){
      const int n = cp*32 + cc*16 + m16;
      #pragma unroll
      for (int c=0; c<4; ++c){
        const int k0 = c*32 + q*8;
        short8 bh, bl;
        #pragma unroll
        for (int jj=0; jj<8; ++jj){
          unsigned short hb_, lb_;
          split_bf(Rm[(k0+jj)*128 + n], hb_, lb_);
          bh[jj] = (short)hb_; bl[jj] = (short)lb_;
        }
        #pragma unroll
        for (int rr=0; rr<2; ++rr){
          acc[rr][cc] = mfma16(Ah[rr][c], bh, acc[rr][cc]);
          acc[rr][cc] = mfma16(Al[rr][c], bh, acc[rr][cc]);
          acc[rr][cc] = mfma16(Ah[rr][c], bl, acc[rr][cc]);
        }
      }
    }
    float* Om = ws + ((role == 0) ? OFF_CA : OFF_CB);
    #pragma unroll
    for (int rr=0; rr<2; ++rr){
      #pragma unroll
      for (int cc=0; cc<2; ++cc){
        const int cg  = cp*32 + cc*16 + m16;
        const int rg0 = rt*32 + rr*16 + q*4;
        #pragma unroll
        for (int i=0; i<4; ++i) Om[(rg0+i)*128 + cg] = acc[rr][cc][i];
      }
    }
  } else {                       // Y0 block (128 batch cols per block)
    const int bcolbase = (role - 2) * 128;
    #pragma unroll
    for (int cc=0; cc<2; ++cc){
      const int bcol = bcolbase + cp*32 + cc*16 + m16;
      #pragma unroll
      for (int c=0; c<4; ++c){
        const int k0 = c*32 + q*8;
        const float* xp = X0 + bcol*128 + k0;      // B[k][b] = X0[b][k]
        const f32x4 x0v = *(const f32x4*)xp;
        const f32x4 x1v = *(const f32x4*)(xp + 4);
        short8 bh, bl;
        #pragma unroll
        for (int jj=0; jj<4; ++jj){
          unsigned short hb_, lb_;
          split_bf(x0v[jj], hb_, lb_); bh[jj]   = (short)hb_; bl[jj]   = (short)lb_;
          split_bf(x1v[jj], hb_, lb_); bh[jj+4] = (short)hb_; bl[jj+4] = (short)lb_;
        }
        #pragma unroll
        for (int rr=0; rr<2; ++rr){
          acc[rr][cc] = mfma16(Ah[rr][c], bh, acc[rr][cc]);
          acc[rr][cc] = mfma16(Al[rr][c], bh, acc[rr][cc]);
          acc[rr][cc] = mfma16(Ah[rr][c], bl, acc[rr][cc]);
        }
      }
    }
    float* Y0p = ws + OFF_Y0;
    #pragma unroll
    for (int rr=0; rr<2; ++rr){
      #pragma unroll
      for (int cc=0; cc<2; ++cc){
        const int bcol = bcolbase + cp*32 + cc*16 + m16;
        const int rg0  = rt*32 + rr*16 + q*4;
        #pragma unroll
        for (int i=0; i<4; ++i)
          Y0p[(rg0+i)*512 + bcol] = acc[rr][cc][i] + by[rg0+i];
      }
    }
  }
}

// ---------------- K4b: pack M fragments (bf16 hi/lo), S0, h*b2
__global__ __launch_bounds__(1024) void k_pack(float* __restrict__ ws,
    const float* __restrict__ X0, const float* __restrict__ bx)
{
  const int fid = blockIdx.x*1024 + threadIdx.x;
  unsigned short* Mf = (unsigned short*)(ws + OFF_MF);
  if (fid < 8192){               // M frags: tile w(16 rows), chunk c, lane l
    const int w = fid >> 9, c = (fid >> 6) & 7, l = fid & 63;
    const int q = l >> 4, m16 = l & 15;
    const int row = w*16 + m16;            // 0..255 of M = [[A,B],[CA,CB]]
    const int k0 = c*32 + q*8;             // 0..255
    const float* src;
    if (row < 128) src = (k0 < 128) ? (ws + OFF_A  + row*128 + k0)
                                    : (ws + OFF_B  + row*128 + (k0-128));
    else           src = (k0 < 128) ? (ws + OFF_CA + (row-128)*128 + k0)
                                    : (ws + OFF_CB + (row-128)*128 + (k0-128));
    unsigned short* dh = Mf + (size_t)w*8192 + c*1024 + l*8;
    unsigned short* dl = dh + 512;
    #pragma unroll
    for (int j=0; j<8; ++j){
      unsigned short hb_, lb_;
      split_bf(src[j], hb_, lb_);
      dh[j] = hb_; dl[j] = lb_;
    }
  } else if (fid < 40960){       // S0 packed per (wg, tile, lane)
    const int t = fid - 8192;
    const int wg = t >> 10, w = (t >> 6) & 15, l = t & 63;
    const int q = l >> 4, m16 = l & 15;
    const int col = wg*16 + m16;
    const int r0 = w*16 + q*4;
    f32x4 v;
    if (r0 < 128){
      v = *(const f32x4*)(X0 + col*128 + r0);
    } else {
      const float* Y0p = ws + OFF_Y0;
      v[0] = Y0p[(r0-128)*512 + col]; v[1] = Y0p[(r0-127)*512 + col];
      v[2] = Y0p[(r0-126)*512 + col]; v[3] = Y0p[(r0-125)*512 + col];
    }
    *(f32x4*)(ws + OFF_S0P + (size_t)t*4) = v;
  } else {                       // h*b2 packed per (tile, lane)
    const int t2 = fid - 40960;
    const int w = t2 >> 6, l = t2 & 63, q = l >> 4;
    const int r0 = w*16 + q*4;
    f32x4 v;
    #pragma unroll
    for (int i=0; i<4; ++i){
      const int r = r0 + i;
      v[i] = 0.01f * ((r < 128) ? bx[r] : ws[OFF_CBX + (r-128)]);
    }
    *(f32x4*)(ws + OFF_HBP + (size_t)t2*4) = v;
  }
}

// ---------------- K5: 511-step recurrence. 32 WGs x 512 thr.
// NEW structure: each wave owns 16 X rows (tile w) AND 16 Y rows (tile 8+w)
// -> all waves symmetric (1 tanh-pack + 1 plain pack + 1 store each), no
// barrier skew. Y MFMAs issue first, X MFMAs second, so the Y softmax-free
// tail (update+tanh+pack+write) overlaps the X MFMA pipe time. Raw s_barrier
// with lgkmcnt-only drain keeps the global stores off the barrier path
// (counted-vmcnt pattern); stores ride across steps.
__global__ __launch_bounds__(512) void k_main(const float* __restrict__ ws,
                                              float* __restrict__ out)
{
  const unsigned short* Mf = (const unsigned short*)(ws + OFF_MF);
  const float* S0p = ws + OFF_S0P;
  const float* hbp = ws + OFF_HBP;

  __shared__ unsigned short Vb[2][16][264];  // V^T: [buf][col n][state row k], bf16

  const int tid = threadIdx.x, lane = tid & 63, w = tid >> 6, wg = blockIdx.x;
  const int q = lane >> 4, m16 = lane & 15;

  // r2=0 -> X tile w (rows 16w..16w+15), r2=1 -> Y tile 8+w (rows 128+16w..)
  short8 Mh[2][8], Ml[2][8];
  #pragma unroll
  for (int r2=0; r2<2; ++r2){
    const unsigned short* bp = Mf + (size_t)(w + 8*r2)*8192 + lane*8;
    #pragma unroll
    for (int c=0; c<8; ++c){
      Mh[r2][c] = *(const short8*)(bp + c*1024);
      Ml[r2][c] = *(const short8*)(bp + c*1024 + 512);
    }
  }
  f32x4 S[2], hb[2];
  #pragma unroll
  for (int r2=0; r2<2; ++r2){
    S[r2]  = *(const f32x4*)(S0p + (size_t)((wg*16 + w + 8*r2)*64 + lane)*4);
    hb[r2] = *(const f32x4*)(hbp + (size_t)((w + 8*r2)*64 + lane)*4);
  }
  const int r0x = w*16 + q*4;           // owned X rows (V position = row)
  const int r0y = 128 + w*16 + q*4;     // owned Y rows (V position = 128+row)

  { // initial V = [X0_bf16 ; tanh(Y0)]
    union { uint2 u; unsigned short s[4]; } pk;
    #pragma unroll
    for (int i=0; i<4; ++i) pk.s[i] = f2bf(S[0][i]);
    *(uint2*)&Vb[0][m16][r0x] = pk.u;
    #pragma unroll
    for (int i=0; i<4; ++i) pk.s[i] = f2bf(tanh_fast(S[1][i]));
    *(uint2*)&Vb[0][m16][r0y] = pk.u;
  }
  asm volatile("s_waitcnt lgkmcnt(0)" ::: "memory");
  __builtin_amdgcn_s_barrier();
  asm volatile("" ::: "memory");

  float* op = out + (size_t)(wg*16 + m16)*65536 + r0x;   // + t*128

  int cur = 0;
  for (int t = 1; t < 512; ++t){
    const unsigned short* vrow = &Vb[cur][m16][q*8];
    short8 vf[8];
    #pragma unroll
    for (int c=0; c<8; ++c) vf[c] = *(const short8*)(vrow + c*32);

    // Y tile first...
    f32x4 aH1 = (f32x4){0.f,0.f,0.f,0.f}, aL1 = (f32x4){0.f,0.f,0.f,0.f};
    #pragma unroll
    for (int c=0; c<8; ++c){
      aH1 = mfma16(Mh[1][c], vf[c], aH1);
      aL1 = mfma16(Ml[1][c], vf[c], aL1);
    }
    // ...X tile second; Y finish below is independent of these MFMAs and
    // can be scheduled into their shadow.
    f32x4 aH0 = (f32x4){0.f,0.f,0.f,0.f}, aL0 = (f32x4){0.f,0.f,0.f,0.f};
    #pragma unroll
    for (int c=0; c<8; ++c){
      aH0 = mfma16(Mh[0][c], vf[c], aH0);
      aL0 = mfma16(Ml[0][c], vf[c], aL0);
    }
    const int nxt = cur ^ 1;
    { // Y finish: update, tanh, pack, LDS write
      union { uint2 u; unsigned short s[4]; } pk;
      #pragma unroll
      for (int i=0; i<4; ++i){
        S[1][i] += 0.01f*(aH1[i] + aL1[i]) + hb[1][i];
        pk.s[i] = f2bf(tanh_fast(S[1][i]));
      }
      *(uint2*)&Vb[nxt][m16][r0y] = pk.u;
    }
    { // X finish: update, pack, LDS write
      union { uint2 u; unsigned short s[4]; } pk;
      #pragma unroll
      for (int i=0; i<4; ++i){
        S[0][i] += 0.01f*(aH0[i] + aL0[i]) + hb[0][i];
        pk.s[i] = f2bf(S[0][i]);
      }
      *(uint2*)&Vb[nxt][m16][r0x] = pk.u;
    }
    // raw barrier: drain LDS writes only; global stores stay in flight.
    asm volatile("s_waitcnt lgkmcnt(0)" ::: "memory");
    __builtin_amdgcn_s_barrier();
    asm volatile("" ::: "memory");
    cur = nxt;
    // X fp32 store after the barrier: overlaps next step's LDS reads/MFMAs.
    *(f32x4*)(op + (size_t)t*128) = S[0];
  }
}

extern "C" void kernel_launch(void* const* d_in, const int* in_sizes, int n_in,
                              void* d_out, int out_size, void* d_ws, size_t ws_size,
                              hipStream_t stream)
{
  (void)in_sizes; (void)n_in; (void)out_size; (void)ws_size;
  const float* X0  = (const float*)d_in[0];
  const float* GA1 = (const float*)d_in[1];
  const float* GAk = (const float*)d_in[2];
  const float* GAp = (const float*)d_in[3];
  const float* YA  = (const float*)d_in[4];
  const float* UA  = (const float*)d_in[5];
  const float* UB  = (const float*)d_in[6];
  const float* VB  = (const float*)d_in[7];
  const float* SBm = (const float*)d_in[8];
  const float* UC  = (const float*)d_in[9];
  const float* VC  = (const float*)d_in[10];
  const float* SCm = (const float*)d_in[11];
  const float* bx  = (const float*)d_in[12];
  const float* by  = (const float*)d_in[13];
  float* out = (float*)d_out;
  float* ws  = (float*)d_ws;

  k_expm<<<dim3(5),  dim3(1024), 0, stream>>>(UA, UB, VB, UC, VC, ws);
  k_abc <<<dim3(3),  dim3(1024), 0, stream>>>(ws, SBm, SCm, GA1, GAk, GAp, YA);
  k_mid <<<dim3(15), dim3(1024), 0, stream>>>(ws, X0, bx, by, out);
  k_pack<<<dim3(41), dim3(1024), 0, stream>>>(ws, X0, bx);
  k_main<<<dim3(32), dim3(512),  0, stream>>>(ws, out);
}